// Round 10
// baseline (24.036 us; speedup 1.0000x reference)
//
#include <hip/hip_runtime.h>
#include <hip/hip_bf16.h>
#include <math.h>

#define D 256
#define BATCH 2048
#define NREL 500
#define CURV_C 0.01f
#define SQRT_C 0.1f

typedef __attribute__((ext_vector_type(8))) short s16x8;
typedef __attribute__((ext_vector_type(4))) float f32x4;

template<int N>
__device__ __forceinline__ void wave_reduceN(float (&v)[N]) {
    #pragma unroll
    for (int off = 1; off < 64; off <<= 1) {
        #pragma unroll
        for (int i = 0; i < N; ++i) v[i] += __shfl_xor(v[i], off, 64);
    }
}

__device__ __forceinline__ float dot4(float4 a, float4 b) {
    return a.x * b.x + a.y * b.y + a.z * b.z + a.w * b.w;
}
__device__ __forceinline__ float tanh_fast(float x) {
    float e = __expf(2.0f * x);
    return 1.0f - 2.0f / (e + 1.0f);
}
__device__ __forceinline__ float artanh_fast(float z) {
    z = fminf(fmaxf(z, -1.0f + 1e-7f), 1.0f - 1e-7f);
    return 0.5f * __logf((1.0f + z) / (1.0f - z));
}
__device__ __forceinline__ unsigned short f2bf(float x) {
    union { float f; unsigned int u; } c; c.f = x;
    unsigned int r = (c.u + 0x7fffu + ((c.u >> 16) & 1u)) >> 16;
    return (unsigned short)r;
}
__device__ __forceinline__ ushort4 pack_bf4(float4 v) {
    ushort4 h;
    h.x = f2bf(v.x); h.y = f2bf(v.y); h.z = f2bf(v.z); h.w = f2bf(v.w);
    return h;
}

// ---------------- single fused kernel: redundant-but-cheap prep ----------------
// grid (32 m-tiles, 8 n-tiles), 512 thr = 8 waves, 64KB LDS, no workspace.
// Phase 0 (per wave): 8 H rows (packed chains of 4) + 8 Q rows (packed chains
// of 2) -> bf16 rows into swizzled LDS, q2/r2 scalars into LDS.
// Phase 1: R9's MFMA 64x64 tile (wave = 32m x 16n strip) + epilogue.
// LDS rule per array: LDS[row][chunk c] holds global 16B-chunk (c ^ (row&7)).
__global__ __launch_bounds__(512) void fused_kernel(
    const float* __restrict__ ent, const float* __restrict__ rel,
    const int* __restrict__ trip,
    const float* __restrict__ grot, const float* __restrict__ gref,
    const float* __restrict__ attw, const float* __restrict__ bias,
    float* __restrict__ out)
{
    __shared__ __align__(16) unsigned char lds[65536];   // A(Q) @0, B(H) @32768
    __shared__ float q2s[64];
    __shared__ float r2s[64];

    const int t = threadIdx.x;
    const int w = t >> 6, l = t & 63;
    const int m0 = blockIdx.x * 64, n0 = blockIdx.y * 64;

    // per-lane hoisted constants
    const float4 wa = *(const float4*)&attw[4 * l];
    const float4 wb = *(const float4*)&attw[D + 4 * l];
    const float2 ar = ((const float2*)grot)[l];
    const float2 af = ((const float2*)gref)[l];
    const float ca0 = __cosf(ar.x), sa0 = __sinf(ar.x);
    const float ca1 = __cosf(ar.y), sa1 = __sinf(ar.y);
    const float cr0 = __cosf(af.x), sr0 = __sinf(af.x);
    const float cr1 = __cosf(af.y), sr1 = __sinf(af.y);

    // lane's 8B slot within a row: global chunk (l>>1), half (l&1)
    const unsigned ch = (unsigned)(l >> 1);
    const unsigned sub8 = (unsigned)((l & 1) * 8);

    // ---- phase 0a: 8 H rows per wave, packed chains of 4
    #pragma unroll
    for (int g = 0; g < 2; ++g) {
        float4 v[4];
        #pragma unroll
        for (int i = 0; i < 4; ++i) {
            const int gn = n0 + 8 * w + 4 * g + i;
            v[i] = (gn < NREL) ? *(const float4*)&rel[(size_t)gn * D + 4 * l]
                               : make_float4(0.f, 0.f, 0.f, 0.f);
        }
        float cch[4] = { dot4(v[0], v[0]), dot4(v[1], v[1]),
                         dot4(v[2], v[2]), dot4(v[3], v[3]) };
        wave_reduceN(cch);
        #pragma unroll
        for (int i = 0; i < 4; ++i) {
            const int r = 8 * w + 4 * g + i;
            const float n2 = cch[i];
            const float nn = fmaxf(sqrtf(n2), 1e-15f);
            const float f = tanh_fast(SQRT_C * nn) / (SQRT_C * nn);
            const float4 hv = make_float4(f * v[i].x, f * v[i].y, f * v[i].z, f * v[i].w);
            const unsigned off = (unsigned)(r * 512) + ((ch ^ (unsigned)(r & 7)) << 4) + sub8;
            *(ushort4*)(lds + 32768 + off) = pack_bf4(hv);
            if (l == 0) r2s[r] = f * f * n2;
        }
    }

    // ---- phase 0b: 8 Q rows per wave, packed chains of 2
    #pragma unroll
    for (int g = 0; g < 4; ++g) {
        float4 se[2], oe[2];
        #pragma unroll
        for (int i = 0; i < 2; ++i) {
            const int b = m0 + 8 * w + 2 * g + i;
            const int s = trip[3 * b + 0];
            const int o = trip[3 * b + 2];
            se[i] = *(const float4*)&ent[(size_t)s * D + 4 * l];
            oe[i] = *(const float4*)&ent[(size_t)o * D + 4 * l];
        }
        float c1[8] = { dot4(se[0], se[0]), dot4(oe[0], oe[0]),
                        dot4(se[0], wa),    dot4(oe[0], wb),
                        dot4(se[1], se[1]), dot4(oe[1], oe[1]),
                        dot4(se[1], wa),    dot4(oe[1], wb) };
        wave_reduceN(c1);

        float4 mt[2]; float no2v[2];
        #pragma unroll
        for (int i = 0; i < 2; ++i) {
            const float ns2 = c1[4 * i + 0], no2 = c1[4 * i + 1];
            const float dsw = c1[4 * i + 2], dow = c1[4 * i + 3];
            no2v[i] = no2;
            const float ns = fmaxf(sqrtf(ns2), 1e-15f);
            const float no = fmaxf(sqrtf(no2), 1e-15f);
            const float fs = artanh_fast(SQRT_C * ns) / (SQRT_C * ns);
            const float fo = artanh_fast(SQRT_C * no) / (SQRT_C * no);
            const float a = 1.0f / (1.0f + __expf(-(fs * dsw + fo * dow)));
            const float4 st = make_float4(fs * se[i].x, fs * se[i].y,
                                          fs * se[i].z, fs * se[i].w);
            const float4 rot = make_float4(ca0 * st.x - sa0 * st.y, sa0 * st.x + ca0 * st.y,
                                           ca1 * st.z - sa1 * st.w, sa1 * st.z + ca1 * st.w);
            const float4 rfl = make_float4(cr0 * st.x + sr0 * st.y, sr0 * st.x - cr0 * st.y,
                                           cr1 * st.z + sr1 * st.w, sr1 * st.z - cr1 * st.w);
            const float ia = 1.0f - a;
            mt[i] = make_float4(a * rot.x + ia * rfl.x, a * rot.y + ia * rfl.y,
                                a * rot.z + ia * rfl.z, a * rot.w + ia * rfl.w);
        }

        float c2[4] = { dot4(mt[0], mt[0]), dot4(mt[0], oe[0]),
                        dot4(mt[1], mt[1]), dot4(mt[1], oe[1]) };
        wave_reduceN(c2);

        #pragma unroll
        for (int i = 0; i < 2; ++i) {
            const float nm2 = c2[2 * i + 0], mtoe = c2[2 * i + 1];
            const float nm = fmaxf(sqrtf(nm2), 1e-15f);
            const float fm = tanh_fast(SQRT_C * nm) / (SQRT_C * nm);
            const float x2v = fm * fm * nm2;
            const float xy = -fm * mtoe;
            const float c = CURV_C;
            const float A  = 1.0f + 2.0f * c * xy + c * no2v[i];
            const float Bf = 1.0f - c * x2v;
            const float den = fmaxf(1.0f + 2.0f * c * xy + c * c * x2v * no2v[i], 1e-15f);
            const float inv = 1.0f / den;
            const float Afm = A * fm;
            const float4 q = make_float4((Bf * oe[i].x - Afm * mt[i].x) * inv,
                                         (Bf * oe[i].y - Afm * mt[i].y) * inv,
                                         (Bf * oe[i].z - Afm * mt[i].z) * inv,
                                         (Bf * oe[i].w - Afm * mt[i].w) * inv);
            const int r = 8 * w + 2 * g + i;
            const unsigned off = (unsigned)(r * 512) + ((ch ^ (unsigned)(r & 7)) << 4) + sub8;
            *(ushort4*)(lds + off) = pack_bf4(q);
            if (l == 0) {
                const float num2 = A * A * x2v + 2.0f * A * Bf * xy + Bf * Bf * no2v[i];
                q2s[r] = num2 * inv * inv;
            }
        }
    }

    __syncthreads();

    // ---- phase 1: MFMA, wave (wm, wn) owns m-strip [wm*32,+32) x n-strip [wn*16,+16)
    const int wm = w >> 2, wn = w & 3;
    const int lr = l & 15, lk = l >> 4;
    const unsigned sw = (unsigned)((lr & 7) << 4);

    f32x4 acc0 = (f32x4){0.f, 0.f, 0.f, 0.f};
    f32x4 acc1 = (f32x4){0.f, 0.f, 0.f, 0.f};

    const unsigned bbase = (unsigned)((wn * 16 + lr) * 512);
    const unsigned abase = (unsigned)((wm * 32 + lr) * 512);
    #pragma unroll
    for (int ks = 0; ks < 8; ++ks) {
        const unsigned coff = ((unsigned)(ks * 4 + lk) << 4) ^ sw;
        s16x8 b  = *(const s16x8*)(lds + 32768 + bbase + coff);
        s16x8 a0 = *(const s16x8*)(lds + abase + coff);
        s16x8 a1 = *(const s16x8*)(lds + abase + 16 * 512 + coff);
        acc0 = __builtin_amdgcn_mfma_f32_16x16x32_bf16(a0, b, acc0, 0, 0, 0);
        acc1 = __builtin_amdgcn_mfma_f32_16x16x32_bf16(a1, b, acc1, 0, 0, 0);
    }

    // ---- epilogue: C layout col(n)=lane&15, row(m)=(lane>>4)*4+reg
    const int nl = wn * 16 + lr;
    const int n = n0 + nl;
    const bool nok = (n < NREL);
    const float y2v = r2s[nl];
    const float biasv = nok ? bias[n] : 0.f;
    const float c = CURV_C;
    #pragma unroll
    for (int mi = 0; mi < 2; ++mi) {
        const f32x4 acc = mi ? acc1 : acc0;
        #pragma unroll
        for (int rg = 0; rg < 4; ++rg) {
            const int ml = wm * 32 + mi * 16 + lk * 4 + rg;
            const float x2 = q2s[ml];
            const float Bf = 1.0f - c * x2;
            const float xy = -acc[rg];
            const float A  = 1.0f + 2.0f * c * xy + c * y2v;
            const float den = fmaxf(1.0f + 2.0f * c * xy + c * c * x2 * y2v, 1e-15f);
            const float num2 = A * A * x2 + 2.0f * A * Bf * xy + Bf * Bf * y2v;
            if (nok) out[(size_t)(m0 + ml) * NREL + n] = biasv - num2 / (den * den);
        }
    }
}

extern "C" void kernel_launch(void* const* d_in, const int* in_sizes, int n_in,
                              void* d_out, int out_size, void* d_ws, size_t ws_size,
                              hipStream_t stream) {
    const float* ent  = (const float*)d_in[0];   // 20000 x 256
    const float* rel  = (const float*)d_in[1];   // 500 x 256
    const int*   trip = (const int*)d_in[2];     // 2048 x 3
    const float* grot = (const float*)d_in[3];   // 128
    const float* gref = (const float*)d_in[4];   // 128
    const float* attw = (const float*)d_in[5];   // 512
    const float* bias = (const float*)d_in[6];   // 500
    float* out = (float*)d_out;                  // 2048 x 500

    fused_kernel<<<dim3(32, 8), 512, 0, stream>>>(ent, rel, trip, grot, gref,
                                                  attw, bias, out);
}

// Round 11
// 14.295 us; speedup vs baseline: 1.6814x; 1.6814x over previous
//
#include <hip/hip_runtime.h>
#include <hip/hip_bf16.h>
#include <math.h>

#define D 256
#define BATCH 2048
#define NREL 500
#define NRELP 512
#define CURV_C 0.01f
#define SQRT_C 0.1f

typedef __attribute__((ext_vector_type(8))) short s16x8;
typedef __attribute__((ext_vector_type(4))) float f32x4;

template<int N>
__device__ __forceinline__ void wave_reduceN(float (&v)[N]) {
    #pragma unroll
    for (int off = 1; off < 64; off <<= 1) {
        #pragma unroll
        for (int i = 0; i < N; ++i) v[i] += __shfl_xor(v[i], off, 64);
    }
}

__device__ __forceinline__ float dot4(float4 a, float4 b) {
    return a.x * b.x + a.y * b.y + a.z * b.z + a.w * b.w;
}
__device__ __forceinline__ float wave_reduce1(float a) {
    #pragma unroll
    for (int off = 1; off < 64; off <<= 1) a += __shfl_xor(a, off, 64);
    return a;
}
__device__ __forceinline__ float tanh_fast(float x) {
    float e = __expf(2.0f * x);
    return 1.0f - 2.0f / (e + 1.0f);
}
__device__ __forceinline__ float artanh_fast(float z) {
    z = fminf(fmaxf(z, -1.0f + 1e-7f), 1.0f - 1e-7f);
    return 0.5f * __logf((1.0f + z) / (1.0f - z));
}
__device__ __forceinline__ unsigned short f2bf(float x) {
    union { float f; unsigned int u; } c; c.f = x;
    unsigned int r = (c.u + 0x7fffu + ((c.u >> 16) & 1u)) >> 16;
    return (unsigned short)r;
}
__device__ __forceinline__ ushort4 pack_bf4(float4 v) {
    ushort4 h;
    h.x = f2bf(v.x); h.y = f2bf(v.y); h.z = f2bf(v.z); h.w = f2bf(v.w);
    return h;
}

// ---------------- prep: wave-per-row, single 7-wide reduction chain ----------------
// waves [0, NRELP)           -> Hh (bf16 rows, zero-padded) + r2
// waves [NRELP, NRELP+BATCH) -> Qh (bf16 rows) + q2
// Q-row identity: u=rot(se), v=ref(se) (orthogonal, linear) =>
//   mt = fs*(a*u + ia*v); |mt|^2 = fs^2*(a^2*ns2 + 2*a*ia*(u.v) + ia^2*ns2);
//   mt.oe = fs*(a*(u.oe) + ia*(v.oe))  -- all from ONE butterfly chain.
__global__ __launch_bounds__(256) void prep_kernel(
    const float* __restrict__ ent, const float* __restrict__ rel,
    const int* __restrict__ trip,
    const float* __restrict__ grot, const float* __restrict__ gref,
    const float* __restrict__ attw,
    unsigned short* __restrict__ Qh, float* __restrict__ q2out,
    unsigned short* __restrict__ Hh, float* __restrict__ r2out)
{
    const int w = blockIdx.x * 4 + (threadIdx.x >> 6);
    const int l = threadIdx.x & 63;

    if (w < NRELP) {
        const int r = w;
        float4 v = make_float4(0.f, 0.f, 0.f, 0.f);
        if (r < NREL) v = *(const float4*)&rel[(size_t)r * D + 4 * l];
        float n2 = wave_reduce1(dot4(v, v));
        float n = fmaxf(sqrtf(n2), 1e-15f);
        float f = tanh_fast(SQRT_C * n) / (SQRT_C * n);
        float4 hv = make_float4(f * v.x, f * v.y, f * v.z, f * v.w);
        *(ushort4*)&Hh[(size_t)r * D + 4 * l] = pack_bf4(hv);
        if (l == 0) r2out[r] = f * f * n2;
    } else if (w < NRELP + BATCH) {
        const int b = w - NRELP;
        const int s = trip[3 * b + 0];
        const int o = trip[3 * b + 2];
        float4 se = *(const float4*)&ent[(size_t)s * D + 4 * l];
        float4 oe = *(const float4*)&ent[(size_t)o * D + 4 * l];

        const float4 wa = *(const float4*)&attw[4 * l];
        const float4 wb = *(const float4*)&attw[D + 4 * l];
        const float2 ar = ((const float2*)grot)[l];
        const float2 af = ((const float2*)gref)[l];
        const float ca0 = __cosf(ar.x), sa0 = __sinf(ar.x);
        const float ca1 = __cosf(ar.y), sa1 = __sinf(ar.y);
        const float cr0 = __cosf(af.x), sr0 = __sinf(af.x);
        const float cr1 = __cosf(af.y), sr1 = __sinf(af.y);

        // u = rot(se), v = ref(se)  (pre-scale by fs deferred)
        const float4 u = make_float4(ca0 * se.x - sa0 * se.y, sa0 * se.x + ca0 * se.y,
                                     ca1 * se.z - sa1 * se.w, sa1 * se.z + ca1 * se.w);
        const float4 vv = make_float4(cr0 * se.x + sr0 * se.y, sr0 * se.x - cr0 * se.y,
                                      cr1 * se.z + sr1 * se.w, sr1 * se.z - cr1 * se.w);

        float ch[7] = { dot4(se, se), dot4(oe, oe), dot4(se, wa), dot4(oe, wb),
                        dot4(u, vv),  dot4(u, oe),  dot4(vv, oe) };
        wave_reduceN(ch);
        const float ns2 = ch[0], no2 = ch[1], dsw = ch[2], dow = ch[3];
        const float uv = ch[4], uo = ch[5], vo = ch[6];

        const float ns = fmaxf(sqrtf(ns2), 1e-15f);
        const float no = fmaxf(sqrtf(no2), 1e-15f);
        const float fs = artanh_fast(SQRT_C * ns) / (SQRT_C * ns);
        const float fo = artanh_fast(SQRT_C * no) / (SQRT_C * no);
        const float a = 1.0f / (1.0f + __expf(-(fs * dsw + fo * dow)));
        const float ia = 1.0f - a;

        float nm2 = fs * fs * (a * a * ns2 + 2.0f * a * ia * uv + ia * ia * ns2);
        nm2 = fmaxf(nm2, 0.0f);
        const float mtoe = fs * (a * uo + ia * vo);

        const float nm = fmaxf(sqrtf(nm2), 1e-15f);
        const float fm = tanh_fast(SQRT_C * nm) / (SQRT_C * nm);
        const float x2v = fm * fm * nm2;
        const float xy = -fm * mtoe;

        const float c = CURV_C;
        const float A  = 1.0f + 2.0f * c * xy + c * no2;
        const float Bf = 1.0f - c * x2v;
        const float den = fmaxf(1.0f + 2.0f * c * xy + c * c * x2v * no2, 1e-15f);
        const float inv = 1.0f / den;
        const float k = A * fm * fs;        // coeff of (a*u + ia*v) in A*fm*mt
        const float4 q = make_float4((Bf * oe.x - k * (a * u.x + ia * vv.x)) * inv,
                                     (Bf * oe.y - k * (a * u.y + ia * vv.y)) * inv,
                                     (Bf * oe.z - k * (a * u.z + ia * vv.z)) * inv,
                                     (Bf * oe.w - k * (a * u.w + ia * vv.w)) * inv);
        *(ushort4*)&Qh[(size_t)b * D + 4 * l] = pack_bf4(q);
        if (l == 0) {
            const float num2 = A * A * x2v + 2.0f * A * Bf * xy + Bf * Bf * no2;
            q2out[b] = num2 * inv * inv;
        }
    }
}

// ---------------- score: 64x64 tile, single-bf16 MFMA, 64KB LDS, 2 blocks/CU ----------------
// LDS: A @0, B @32768; each [64 rows][256 k] bf16 (512B/row).
// Storage rule: LDS[row][chunk c] holds global 16B-chunk (c ^ (row&7)) of that row.
// Staged via global_load_lds (linear LDS dest, pre-swizzled global source).
__global__ __launch_bounds__(512, 2) void score_kernel(
    const unsigned short* __restrict__ Qh, const float* __restrict__ q2,
    const unsigned short* __restrict__ Hh, const float* __restrict__ r2,
    const float* __restrict__ bias, float* __restrict__ out)
{
    __shared__ __align__(16) unsigned char lds[65536];
    const int t = threadIdx.x;
    const int m0 = blockIdx.x * 64, n0 = blockIdx.y * 64;
    const int w = t >> 6, l = t & 63;

    // ---- stage: wave w fills rows [w*8, w*8+8) of both arrays
    {
        const int rsub = l >> 5;         // 0,1
        const int cl = l & 31;           // 16B chunk within row
        #pragma unroll
        for (int it = 0; it < 4; ++it) {
            const int r = w * 8 + it * 2 + rsub;
            const unsigned csw = (unsigned)((cl ^ (r & 7)) * 8);   // elem offset
            const unsigned loff = (unsigned)(w * 4096 + it * 1024);
            const size_t gA = (size_t)(m0 + r) * D + csw;
            const size_t gB = (size_t)(n0 + r) * D + csw;
            __builtin_amdgcn_global_load_lds(
                (const __attribute__((address_space(1))) void*)(Qh + gA),
                (__attribute__((address_space(3))) void*)(lds + loff), 16, 0, 0);
            __builtin_amdgcn_global_load_lds(
                (const __attribute__((address_space(1))) void*)(Hh + gB),
                (__attribute__((address_space(3))) void*)(lds + 32768 + loff), 16, 0, 0);
        }
    }
    __syncthreads();

    // ---- MFMA: wave (wm, wn) owns m-strip [wm*32,+32) x n-strip [wn*16,+16)
    const int wm = w >> 2, wn = w & 3;
    const int lr = l & 15, lk = l >> 4;
    const unsigned sw = (unsigned)((lr & 7) << 4);

    f32x4 acc0 = (f32x4){0.f, 0.f, 0.f, 0.f};
    f32x4 acc1 = (f32x4){0.f, 0.f, 0.f, 0.f};

    const unsigned bbase = (unsigned)((wn * 16 + lr) * 512);
    const unsigned abase = (unsigned)((wm * 32 + lr) * 512);
    #pragma unroll
    for (int ks = 0; ks < 8; ++ks) {
        const unsigned coff = ((unsigned)(ks * 4 + lk) << 4) ^ sw;
        s16x8 b  = *(const s16x8*)(lds + 32768 + bbase + coff);
        s16x8 a0 = *(const s16x8*)(lds + abase + coff);
        s16x8 a1 = *(const s16x8*)(lds + abase + 16 * 512 + coff);
        acc0 = __builtin_amdgcn_mfma_f32_16x16x32_bf16(a0, b, acc0, 0, 0, 0);
        acc1 = __builtin_amdgcn_mfma_f32_16x16x32_bf16(a1, b, acc1, 0, 0, 0);
    }

    // ---- epilogue: C layout col(n)=lane&15, row(m)=(lane>>4)*4+reg
    const int n = n0 + wn * 16 + lr;
    const bool nok = (n < NREL);
    const float y2v = nok ? r2[n] : 0.f;
    const float biasv = nok ? bias[n] : 0.f;
    const float c = CURV_C;
    #pragma unroll
    for (int mi = 0; mi < 2; ++mi) {
        const f32x4 acc = mi ? acc1 : acc0;
        #pragma unroll
        for (int rg = 0; rg < 4; ++rg) {
            const int m = m0 + wm * 32 + mi * 16 + lk * 4 + rg;
            const float x2 = q2[m];
            const float Bf = 1.0f - c * x2;
            const float xy = -acc[rg];
            const float A  = 1.0f + 2.0f * c * xy + c * y2v;
            const float den = fmaxf(1.0f + 2.0f * c * xy + c * c * x2 * y2v, 1e-15f);
            const float num2 = A * A * x2 + 2.0f * A * Bf * xy + Bf * Bf * y2v;
            if (nok) out[(size_t)m * NREL + n] = biasv - num2 / (den * den);
        }
    }
}

extern "C" void kernel_launch(void* const* d_in, const int* in_sizes, int n_in,
                              void* d_out, int out_size, void* d_ws, size_t ws_size,
                              hipStream_t stream) {
    const float* ent  = (const float*)d_in[0];   // 20000 x 256
    const float* rel  = (const float*)d_in[1];   // 500 x 256
    const int*   trip = (const int*)d_in[2];     // 2048 x 3
    const float* grot = (const float*)d_in[3];   // 128
    const float* gref = (const float*)d_in[4];   // 128
    const float* attw = (const float*)d_in[5];   // 512
    const float* bias = (const float*)d_in[6];   // 500
    float* out = (float*)d_out;                  // 2048 x 500

    char* ws = (char*)d_ws;
    unsigned short* Qh = (unsigned short*)(ws);                       // 1 MB
    unsigned short* Hh = (unsigned short*)(ws + (1u << 20));          // 256 KB
    float* q2 = (float*)(ws + (1u << 20) + (256u << 10));             // 8 KB
    float* r2 = (float*)(ws + (1u << 20) + (256u << 10) + 8192);      // 2 KB

    const int nwaves = NRELP + BATCH;            // 2560
    prep_kernel<<<nwaves / 4, 256, 0, stream>>>(ent, rel, trip, grot, gref, attw,
                                                Qh, q2, Hh, r2);
    dim3 grid(BATCH / 64, NRELP / 64);
    score_kernel<<<grid, 512, 0, stream>>>(Qh, q2, Hh, r2, bias, out);
}

// Round 12
// 13.839 us; speedup vs baseline: 1.7368x; 1.0330x over previous
//
#include <hip/hip_runtime.h>
#include <hip/hip_bf16.h>
#include <math.h>

#define D 256
#define BATCH 2048
#define NREL 500
#define NRELP 512
#define CURV_C 0.01f
#define SQRT_C 0.1f

typedef __attribute__((ext_vector_type(8))) short s16x8;
typedef __attribute__((ext_vector_type(4))) float f32x4;

template<int N>
__device__ __forceinline__ void wave_reduceN(float (&v)[N]) {
    #pragma unroll
    for (int off = 1; off < 64; off <<= 1) {
        #pragma unroll
        for (int i = 0; i < N; ++i) v[i] += __shfl_xor(v[i], off, 64);
    }
}

__device__ __forceinline__ float dot4(float4 a, float4 b) {
    return a.x * b.x + a.y * b.y + a.z * b.z + a.w * b.w;
}
__device__ __forceinline__ float wave_reduce1(float a) {
    #pragma unroll
    for (int off = 1; off < 64; off <<= 1) a += __shfl_xor(a, off, 64);
    return a;
}
__device__ __forceinline__ float tanh_fast(float x) {
    float e = __expf(2.0f * x);
    return 1.0f - 2.0f / (e + 1.0f);
}
__device__ __forceinline__ float artanh_fast(float z) {
    z = fminf(fmaxf(z, -1.0f + 1e-7f), 1.0f - 1e-7f);
    return 0.5f * __logf((1.0f + z) / (1.0f - z));
}
__device__ __forceinline__ unsigned short f2bf(float x) {
    union { float f; unsigned int u; } c; c.f = x;
    unsigned int r = (c.u + 0x7fffu + ((c.u >> 16) & 1u)) >> 16;
    return (unsigned short)r;
}
__device__ __forceinline__ ushort4 pack_bf4(float4 v) {
    ushort4 h;
    h.x = f2bf(v.x); h.y = f2bf(v.y); h.z = f2bf(v.z); h.w = f2bf(v.w);
    return h;
}

// ---------------- prep: wave-per-row; Q waves first (long critical path) ----------------
// waves [0, BATCH)              -> Qh (bf16 rows) + q2
// waves [BATCH, BATCH+NRELP)    -> Hh (bf16 rows, zero-padded) + r2
// Q-row identity: u=rot(se), v=ref(se) (orthogonal, linear) =>
//   mt = fs*(a*u + ia*v); |mt|^2 = fs^2*(a^2+ia^2)*ns2 + 2*a*ia*fs^2*(u.v);
//   mt.oe = fs*(a*(u.oe) + ia*(v.oe))  -- all from ONE 7-wide butterfly chain.
__global__ __launch_bounds__(256) void prep_kernel(
    const float* __restrict__ ent, const float* __restrict__ rel,
    const int* __restrict__ trip,
    const float* __restrict__ grot, const float* __restrict__ gref,
    const float* __restrict__ attw,
    unsigned short* __restrict__ Qh, float* __restrict__ q2out,
    unsigned short* __restrict__ Hh, float* __restrict__ r2out)
{
    const int w = blockIdx.x * 4 + (threadIdx.x >> 6);
    const int l = threadIdx.x & 63;

    if (w < BATCH) {
        const int b = w;
        const int s = trip[3 * b + 0];
        const int o = trip[3 * b + 2];
        float4 se = *(const float4*)&ent[(size_t)s * D + 4 * l];
        float4 oe = *(const float4*)&ent[(size_t)o * D + 4 * l];

        const float4 wa = *(const float4*)&attw[4 * l];
        const float4 wb = *(const float4*)&attw[D + 4 * l];
        const float2 ar = ((const float2*)grot)[l];
        const float2 af = ((const float2*)gref)[l];
        const float ca0 = __cosf(ar.x), sa0 = __sinf(ar.x);
        const float ca1 = __cosf(ar.y), sa1 = __sinf(ar.y);
        const float cr0 = __cosf(af.x), sr0 = __sinf(af.x);
        const float cr1 = __cosf(af.y), sr1 = __sinf(af.y);

        // u = rot(se), v = ref(se)  (fs scaling deferred)
        const float4 u = make_float4(ca0 * se.x - sa0 * se.y, sa0 * se.x + ca0 * se.y,
                                     ca1 * se.z - sa1 * se.w, sa1 * se.z + ca1 * se.w);
        const float4 vv = make_float4(cr0 * se.x + sr0 * se.y, sr0 * se.x - cr0 * se.y,
                                      cr1 * se.z + sr1 * se.w, sr1 * se.z - cr1 * se.w);

        float ch[7] = { dot4(se, se), dot4(oe, oe), dot4(se, wa), dot4(oe, wb),
                        dot4(u, vv),  dot4(u, oe),  dot4(vv, oe) };
        wave_reduceN(ch);
        const float ns2 = ch[0], no2 = ch[1], dsw = ch[2], dow = ch[3];
        const float uv = ch[4], uo = ch[5], vo = ch[6];

        const float ns = fmaxf(sqrtf(ns2), 1e-15f);
        const float no = fmaxf(sqrtf(no2), 1e-15f);
        const float fs = artanh_fast(SQRT_C * ns) / (SQRT_C * ns);
        const float fo = artanh_fast(SQRT_C * no) / (SQRT_C * no);
        const float a = 1.0f / (1.0f + __expf(-(fs * dsw + fo * dow)));
        const float ia = 1.0f - a;

        float nm2 = fs * fs * ((a * a + ia * ia) * ns2 + 2.0f * a * ia * uv);
        nm2 = fmaxf(nm2, 0.0f);
        const float mtoe = fs * (a * uo + ia * vo);

        const float nm = fmaxf(sqrtf(nm2), 1e-15f);
        const float fm = tanh_fast(SQRT_C * nm) / (SQRT_C * nm);
        const float x2v = fm * fm * nm2;
        const float xy = -fm * mtoe;

        const float c = CURV_C;
        const float A  = 1.0f + 2.0f * c * xy + c * no2;
        const float Bf = 1.0f - c * x2v;
        const float den = fmaxf(1.0f + 2.0f * c * xy + c * c * x2v * no2, 1e-15f);
        const float inv = 1.0f / den;
        const float k = A * fm * fs;        // coeff of (a*u + ia*v)
        const float4 q = make_float4((Bf * oe.x - k * (a * u.x + ia * vv.x)) * inv,
                                     (Bf * oe.y - k * (a * u.y + ia * vv.y)) * inv,
                                     (Bf * oe.z - k * (a * u.z + ia * vv.z)) * inv,
                                     (Bf * oe.w - k * (a * u.w + ia * vv.w)) * inv);
        *(ushort4*)&Qh[(size_t)b * D + 4 * l] = pack_bf4(q);
        if (l == 0) {
            const float num2 = A * A * x2v + 2.0f * A * Bf * xy + Bf * Bf * no2;
            q2out[b] = num2 * inv * inv;
        }
    } else if (w < BATCH + NRELP) {
        const int r = w - BATCH;
        float4 v = make_float4(0.f, 0.f, 0.f, 0.f);
        if (r < NREL) v = *(const float4*)&rel[(size_t)r * D + 4 * l];
        float n2 = wave_reduce1(dot4(v, v));
        float n = fmaxf(sqrtf(n2), 1e-15f);
        float f = tanh_fast(SQRT_C * n) / (SQRT_C * n);
        float4 hv = make_float4(f * v.x, f * v.y, f * v.z, f * v.w);
        *(ushort4*)&Hh[(size_t)r * D + 4 * l] = pack_bf4(hv);
        if (l == 0) r2out[r] = f * f * n2;
    }
}

// ---------------- score: 64x64 tile, single-bf16 MFMA, 64KB LDS, 2 blocks/CU ----------------
// LDS: A @0, B @32768; each [64 rows][256 k] bf16 (512B/row).
// Storage rule: LDS[row][chunk c] holds global 16B-chunk (c ^ (row&7)) of that row.
// Staged via global_load_lds (linear LDS dest, pre-swizzled global source).
__global__ __launch_bounds__(512, 2) void score_kernel(
    const unsigned short* __restrict__ Qh, const float* __restrict__ q2,
    const unsigned short* __restrict__ Hh, const float* __restrict__ r2,
    const float* __restrict__ bias, float* __restrict__ out)
{
    __shared__ __align__(16) unsigned char lds[65536];
    const int t = threadIdx.x;
    const int m0 = blockIdx.x * 64, n0 = blockIdx.y * 64;
    const int w = t >> 6, l = t & 63;

    // ---- stage: wave w fills rows [w*8, w*8+8) of both arrays
    {
        const int rsub = l >> 5;         // 0,1
        const int cl = l & 31;           // 16B chunk within row
        #pragma unroll
        for (int it = 0; it < 4; ++it) {
            const int r = w * 8 + it * 2 + rsub;
            const unsigned csw = (unsigned)((cl ^ (r & 7)) * 8);   // elem offset
            const unsigned loff = (unsigned)(w * 4096 + it * 1024);
            const size_t gA = (size_t)(m0 + r) * D + csw;
            const size_t gB = (size_t)(n0 + r) * D + csw;
            __builtin_amdgcn_global_load_lds(
                (const __attribute__((address_space(1))) void*)(Qh + gA),
                (__attribute__((address_space(3))) void*)(lds + loff), 16, 0, 0);
            __builtin_amdgcn_global_load_lds(
                (const __attribute__((address_space(1))) void*)(Hh + gB),
                (__attribute__((address_space(3))) void*)(lds + 32768 + loff), 16, 0, 0);
        }
    }

    // ---- issue epilogue scalar loads early (hide under stage drain + MFMA)
    const int wm = w >> 2, wn = w & 3;
    const int lr = l & 15, lk = l >> 4;
    const int n = n0 + wn * 16 + lr;
    const bool nok = (n < NREL);
    const float y2v = nok ? r2[n] : 0.f;
    const float biasv = nok ? bias[n] : 0.f;
    float x2a[2][4];
    #pragma unroll
    for (int mi = 0; mi < 2; ++mi)
        #pragma unroll
        for (int rg = 0; rg < 4; ++rg)
            x2a[mi][rg] = q2[m0 + wm * 32 + mi * 16 + lk * 4 + rg];

    __syncthreads();

    // ---- MFMA: wave (wm, wn) owns m-strip [wm*32,+32) x n-strip [wn*16,+16)
    const unsigned sw = (unsigned)((lr & 7) << 4);

    f32x4 acc0 = (f32x4){0.f, 0.f, 0.f, 0.f};
    f32x4 acc1 = (f32x4){0.f, 0.f, 0.f, 0.f};

    const unsigned bbase = (unsigned)((wn * 16 + lr) * 512);
    const unsigned abase = (unsigned)((wm * 32 + lr) * 512);
    #pragma unroll
    for (int ks = 0; ks < 8; ++ks) {
        const unsigned coff = ((unsigned)(ks * 4 + lk) << 4) ^ sw;
        s16x8 b  = *(const s16x8*)(lds + 32768 + bbase + coff);
        s16x8 a0 = *(const s16x8*)(lds + abase + coff);
        s16x8 a1 = *(const s16x8*)(lds + abase + 16 * 512 + coff);
        acc0 = __builtin_amdgcn_mfma_f32_16x16x32_bf16(a0, b, acc0, 0, 0, 0);
        acc1 = __builtin_amdgcn_mfma_f32_16x16x32_bf16(a1, b, acc1, 0, 0, 0);
    }

    // ---- epilogue: C layout col(n)=lane&15, row(m)=(lane>>4)*4+reg
    const float c = CURV_C;
    #pragma unroll
    for (int mi = 0; mi < 2; ++mi) {
        const f32x4 acc = mi ? acc1 : acc0;
        #pragma unroll
        for (int rg = 0; rg < 4; ++rg) {
            const int m = m0 + wm * 32 + mi * 16 + lk * 4 + rg;
            const float x2 = x2a[mi][rg];
            const float Bf = 1.0f - c * x2;
            const float xy = -acc[rg];
            const float A  = 1.0f + 2.0f * c * xy + c * y2v;
            const float den = fmaxf(1.0f + 2.0f * c * xy + c * c * x2 * y2v, 1e-15f);
            const float num2 = A * A * x2 + 2.0f * A * Bf * xy + Bf * Bf * y2v;
            if (nok) out[(size_t)m * NREL + n] = biasv - num2 / (den * den);
        }
    }
}

extern "C" void kernel_launch(void* const* d_in, const int* in_sizes, int n_in,
                              void* d_out, int out_size, void* d_ws, size_t ws_size,
                              hipStream_t stream) {
    const float* ent  = (const float*)d_in[0];   // 20000 x 256
    const float* rel  = (const float*)d_in[1];   // 500 x 256
    const int*   trip = (const int*)d_in[2];     // 2048 x 3
    const float* grot = (const float*)d_in[3];   // 128
    const float* gref = (const float*)d_in[4];   // 128
    const float* attw = (const float*)d_in[5];   // 512
    const float* bias = (const float*)d_in[6];   // 500
    float* out = (float*)d_out;                  // 2048 x 500

    char* ws = (char*)d_ws;
    unsigned short* Qh = (unsigned short*)(ws);                       // 1 MB
    unsigned short* Hh = (unsigned short*)(ws + (1u << 20));          // 256 KB
    float* q2 = (float*)(ws + (1u << 20) + (256u << 10));             // 8 KB
    float* r2 = (float*)(ws + (1u << 20) + (256u << 10) + 8192);      // 2 KB

    const int nwaves = BATCH + NRELP;            // 2560
    prep_kernel<<<nwaves / 4, 256, 0, stream>>>(ent, rel, trip, grot, gref, attw,
                                                Qh, q2, Hh, r2);
    dim3 grid(BATCH / 64, NRELP / 64);
    score_kernel<<<grid, 512, 0, stream>>>(Qh, q2, Hh, r2, bias, out);
}